// Round 8
// baseline (1770.050 us; speedup 1.0000x reference)
//
#include <hip/hip_runtime.h>

// Problem constants — NOTE: BS=4 (H, DH, BS, NSEL, WIN = 16, 64, 4, 4, 32)
constexpr int cH = 16, cDH = 64, cBS = 4, cNSEL = 4, cWIN = 32;
constexpr int cB = 2, cS = 1024, cD = 1024;
constexpr int cNB = 256, cNBLK = 257, cDFF = 4096, cM = 2048; // cM = B*S
constexpr float cSCALE = 0.125f; // DH^-0.5

__device__ __forceinline__ float sigf(float x) { return 1.f / (1.f + expf(-x)); }

__global__ __launch_bounds__(256) void k_fill(float* __restrict__ p, float v)
{
  p[blockIdx.x * 256 + threadIdx.x] = v;
}

// ---------------- xr = l0*x + l1*x0 ; h = rmsnorm(xr) ----------------
__global__ __launch_bounds__(256) void k_lerp_rmsnorm(
    const float* __restrict__ x, const float* __restrict__ x0,
    const float* __restrict__ lambdas, float* __restrict__ xr, float* __restrict__ h)
{
  int row = blockIdx.x, tid = threadIdx.x;
  float l0 = lambdas[0], l1 = lambdas[1];
  size_t base = (size_t)row * cD + tid * 4;
  float4 xa = *(const float4*)(x + base);
  float4 xb = *(const float4*)(x0 + base);
  float v0 = l0 * xa.x + l1 * xb.x;
  float v1 = l0 * xa.y + l1 * xb.y;
  float v2 = l0 * xa.z + l1 * xb.z;
  float v3 = l0 * xa.w + l1 * xb.w;
  float ss = v0*v0 + v1*v1 + v2*v2 + v3*v3;
  #pragma unroll
  for (int o = 32; o; o >>= 1) ss += __shfl_xor(ss, o);
  __shared__ float red[4];
  if ((tid & 63) == 0) red[tid >> 6] = ss;
  __syncthreads();
  float tot = red[0] + red[1] + red[2] + red[3];
  float sc = rsqrtf(tot * (1.0f / cD) + 1e-6f);
  *(float4*)(xr + base) = make_float4(v0, v1, v2, v3);
  *(float4*)(h + base)  = make_float4(v0*sc, v1*sc, v2*sc, v3*sc);
}

// ---------------- out = rmsnorm(x) ----------------
__global__ __launch_bounds__(256) void k_rmsnorm(const float* __restrict__ x, float* __restrict__ out)
{
  int row = blockIdx.x, tid = threadIdx.x;
  size_t base = (size_t)row * cD + tid * 4;
  float4 v = *(const float4*)(x + base);
  float ss = v.x*v.x + v.y*v.y + v.z*v.z + v.w*v.w;
  #pragma unroll
  for (int o = 32; o; o >>= 1) ss += __shfl_xor(ss, o);
  __shared__ float red[4];
  if ((tid & 63) == 0) red[tid >> 6] = ss;
  __syncthreads();
  float tot = red[0] + red[1] + red[2] + red[3];
  float sc = rsqrtf(tot * (1.0f / cD) + 1e-6f);
  *(float4*)(out + base) = make_float4(v.x*sc, v.y*sc, v.z*sc, v.w*sc);
}

// ---------------- tiled f32 GEMM: C = epi(A@B) + R ; EPI: 0=none, 1=relu^2 ----------------
template<int EPI>
__global__ __launch_bounds__(256) void k_gemm(
    const float* __restrict__ A, const float* __restrict__ Bw,
    const float* __restrict__ R, float* __restrict__ C, int M, int N, int K)
{
  constexpr int BM = 64, BN = 64, BK = 16;
  __shared__ float As[BK][BM];
  __shared__ float Bs[BK][BN];
  int tid = threadIdx.x;
  int tx = tid & 15, ty = tid >> 4;
  int m0 = blockIdx.y * BM, n0 = blockIdx.x * BN;
  float acc[4][4] = {};
  for (int k0 = 0; k0 < K; k0 += BK) {
    {
      int r = tid >> 2, c4 = (tid & 3) << 2;
      float4 av = *(const float4*)(A + (size_t)(m0 + r) * K + k0 + c4);
      As[c4+0][r] = av.x; As[c4+1][r] = av.y; As[c4+2][r] = av.z; As[c4+3][r] = av.w;
    }
    {
      int kr = tid >> 4, c4 = (tid & 15) << 2;
      int n = n0 + c4;
      const float* bp = Bw + (size_t)(k0 + kr) * N;
      if (n + 3 < N) {
        float4 bv = *(const float4*)(bp + n);
        Bs[kr][c4+0] = bv.x; Bs[kr][c4+1] = bv.y; Bs[kr][c4+2] = bv.z; Bs[kr][c4+3] = bv.w;
      } else {
        #pragma unroll
        for (int j = 0; j < 4; j++) Bs[kr][c4+j] = (n + j < N) ? bp[n + j] : 0.f;
      }
    }
    __syncthreads();
    #pragma unroll
    for (int kk = 0; kk < BK; ++kk) {
      float4 a4 = *(const float4*)&As[kk][ty << 2];
      float4 b4 = *(const float4*)&Bs[kk][tx << 2];
      float av[4] = {a4.x, a4.y, a4.z, a4.w};
      float bv[4] = {b4.x, b4.y, b4.z, b4.w};
      #pragma unroll
      for (int i = 0; i < 4; i++)
        #pragma unroll
        for (int j = 0; j < 4; j++) acc[i][j] += av[i] * bv[j];
    }
    __syncthreads();
  }
  #pragma unroll
  for (int i = 0; i < 4; i++) {
    int m = m0 + (ty << 2) + i;
    #pragma unroll
    for (int j = 0; j < 4; j++) {
      int n = n0 + (tx << 2) + j;
      if (n < N) {
        float vv = acc[i][j];
        if (EPI == 1) vv = vv > 0.f ? vv * vv : 0.f;
        if (R) vv += R[(size_t)m * N + n];
        C[(size_t)m * N + n] = vv;
      }
    }
  }
}

// ---------------- block compression (BS=4): kc/vc (B,257,H,DH) ----------------
__global__ __launch_bounds__(64) void k_compress4(
    const float* __restrict__ kbuf, const float* __restrict__ vbuf,
    const float* __restrict__ pos_k, const float* __restrict__ pos_v,
    const float* __restrict__ Wck, const float* __restrict__ Wcv,
    const float* __restrict__ mem_k, const float* __restrict__ mem_v,
    float* __restrict__ kc, float* __restrict__ vc)
{
  int idx = blockIdx.x;          // b*NBLK*H + n*H + h
  int h = idx % cH; int n = (idx / cH) % cNBLK; int b = idx / (cH * cNBLK);
  int d = threadIdx.x;
  size_t co = (((size_t)b * cNBLK + n) * cH + h) * cDH + d;
  if (n == 0) {
    kc[co] = mem_k[h * cDH + d];
    vc[co] = mem_v[h * cDH + d];
    return;
  }
  __shared__ float kb[cBS * cDH], vb[cBS * cDH]; // 256 each
  int nb = n - 1;
  for (int t = d; t < cBS * cDH; t += 64) {
    int i = t >> 6, e = t & 63; // i<4
    size_t src = (((size_t)b * cS + nb * cBS + i) * cH + h) * cDH + e;
    kb[t] = kbuf[src] + pos_k[(h * cBS + i) * cDH + e];
    vb[t] = vbuf[src] + pos_v[(h * cBS + i) * cDH + e];
  }
  __syncthreads();
  float ak = 0.f, av = 0.f;
  for (int j = 0; j < cBS * cDH; ++j) { // Wck: (256,64)
    ak += kb[j] * Wck[(size_t)j * cDH + d];
    av += vb[j] * Wcv[(size_t)j * cDH + d];
  }
  kc[co] = ak; vc[co] = av;
}

// ---------------- compressed attention over 257 blocks + top-4 of 256 ----------------
__global__ __launch_bounds__(64) void k_cattn4(
    const float* __restrict__ q, const float* __restrict__ kc, const float* __restrict__ vc,
    float* __restrict__ cout, float* __restrict__ sel_val, int* __restrict__ sel_idx)
{
  int s = blockIdx.x % cS; int h = (blockIdx.x / cS) % cH; int b = blockIdx.x / (cS * cH);
  int lane = threadIdx.x;
  __shared__ float qs[cDH];
  __shared__ float p[cNBLK]; // 257
  qs[lane] = q[(((size_t)b * cS + s) * cH + h) * cDH + lane];
  __syncthreads();
  // scores: 5 rounds cover n = lane + r*64 in [0, 320)
  float sc[5];
  float lmx = -INFINITY;
  #pragma unroll
  for (int r = 0; r < 5; r++) {
    int n = lane + r * 64;
    sc[r] = -INFINITY;
    if (n < cNBLK) {
      bool vis = (n == 0) || ((n - 1) * cBS + (cBS - 1) <= s); // block_last <= s
      if (vis) {
        const float* kp = kc + (((size_t)b * cNBLK + n) * cH + h) * cDH;
        float a = 0.f;
        #pragma unroll 16
        for (int e = 0; e < cDH; e++) a += qs[e] * kp[e];
        sc[r] = a * cSCALE;
        lmx = fmaxf(lmx, sc[r]);
      }
    }
  }
  #pragma unroll
  for (int o = 32; o; o >>= 1) lmx = fmaxf(lmx, __shfl_xor(lmx, o));
  float lsum = 0.f;
  #pragma unroll
  for (int r = 0; r < 5; r++) {
    int n = lane + r * 64;
    float e = (sc[r] == -INFINITY) ? 0.f : expf(sc[r] - lmx);
    sc[r] = e; lsum += e;
    if (n < cNBLK) p[n] = e;
  }
  #pragma unroll
  for (int o = 32; o; o >>= 1) lsum += __shfl_xor(lsum, o);
  float inv = 1.f / lsum;
  #pragma unroll
  for (int r = 0; r < 5; r++) {
    int n = lane + r * 64;
    if (n < cNBLK) p[n] *= inv;
  }
  __syncthreads();
  // cout = sum_n p[n] * vc[b,n,h,lane]
  float acc = 0.f;
  for (int n = 0; n < cNBLK; n++)
    acc += p[n] * vc[(((size_t)b * cNBLK + n) * cH + h) * cDH + lane];
  cout[(((size_t)b * cS + s) * cH + h) * cDH + lane] = acc;
  // top-4 over p[1..256] (serial, strict > => lowest index on ties, like lax.top_k)
  if (lane == 0) {
    size_t so = (((size_t)b * cH + h) * cS + s) * cNSEL;
    float taken[cNSEL]; int takeni[cNSEL];
    for (int t = 0; t < cNSEL; t++) {
      float best = -1.f; int bi = 0;
      for (int j = 0; j < cNB; j++) {
        float pv = p[j + 1];
        bool skip = false;
        for (int u = 0; u < t; u++) if (takeni[u] == j) { skip = true; break; }
        if (!skip && pv > best) { best = pv; bi = j; }
      }
      taken[t] = best; takeni[t] = bi;
      sel_val[so + t] = best; sel_idx[so + t] = bi;
    }
  }
}

// ---------------- in-place RoPE on q and k ----------------
__global__ __launch_bounds__(256) void k_rope(float* __restrict__ q, float* __restrict__ k)
{
  int t = blockIdx.x * 256 + threadIdx.x; // < B*S*H*32
  int j = t & 31; int h = (t >> 5) & (cH - 1); int bs = t >> 9;
  int s = bs & (cS - 1);
  float inv = expf(-(float)j * 0.28782313662425575f); // ln(10000)/32
  float ang = (float)s * inv;
  float sn, c; sincosf(ang, &sn, &c);
  size_t base = ((size_t)bs * cH + h) * cDH;
  float q1 = q[base + j], q2 = q[base + j + 32];
  q[base + j]      = q1 * c - q2 * sn;
  q[base + j + 32] = q1 * sn + q2 * c;
  float k1 = k[base + j], k2 = k[base + j + 32];
  k[base + j]      = k1 * c - k2 * sn;
  k[base + j + 32] = k1 * sn + k2 * c;
}

// ---------------- fine attention: 5 blocks x 4 keys = 20 ----------------
__global__ __launch_bounds__(64) void k_fattn4(
    const float* __restrict__ qr, const float* __restrict__ kr, const float* __restrict__ v,
    const float* __restrict__ sel_val, const int* __restrict__ sel_idx,
    float* __restrict__ fout)
{
  int s = blockIdx.x % cS; int h = (blockIdx.x / cS) % cH; int b = blockIdx.x / (cS * cH);
  int lane = threadIdx.x;
  const int NK = 5 * cBS; // 20
  __shared__ float qs[cDH];
  __shared__ float p[NK];
  __shared__ int blk[5];
  __shared__ int bok[5];
  qs[lane] = qr[(((size_t)b * cS + s) * cH + h) * cDH + lane];
  if (lane < 5) {
    size_t so = (((size_t)b * cH + h) * cS + s) * cNSEL;
    if (lane < 4) { blk[lane] = sel_idx[so + lane]; bok[lane] = sel_val[so + lane] > 0.f; }
    else          { blk[4] = s / cBS; bok[4] = 1; }
  }
  __syncthreads();
  float sc = -INFINITY;
  if (lane < NK) {
    int t = lane >> 2, i = lane & 3;
    int kpos = blk[t] * cBS + i;
    if (bok[t] && kpos <= s) {
      const float* kp = kr + (((size_t)b * cS + kpos) * cH + h) * cDH;
      float a = 0.f;
      #pragma unroll 16
      for (int e = 0; e < cDH; e++) a += qs[e] * kp[e];
      sc = a * cSCALE;
    }
  }
  float mx = sc;
  #pragma unroll
  for (int o = 32; o; o >>= 1) mx = fmaxf(mx, __shfl_xor(mx, o));
  float ex = (sc == -INFINITY) ? 0.f : expf(sc - mx);
  float sum = ex;
  #pragma unroll
  for (int o = 32; o; o >>= 1) sum += __shfl_xor(sum, o);
  if (lane < NK) p[lane] = ex / sum;
  __syncthreads();
  float acc = 0.f;
  for (int t = 0; t < 5; t++) {
    if (!bok[t]) continue; // wave-uniform
    int kbase = blk[t] * cBS;
    #pragma unroll
    for (int i = 0; i < cBS; i++) {
      float pm = p[t * cBS + i];
      if (pm != 0.f)
        acc += pm * v[(((size_t)b * cS + kbase + i) * cH + h) * cDH + lane];
    }
  }
  fout[(((size_t)b * cS + s) * cH + h) * cDH + lane] = acc;
}

// ---------------- sliding-window attention (WIN=32) ----------------
__global__ __launch_bounds__(64) void k_sattn(
    const float* __restrict__ qr, const float* __restrict__ kr, const float* __restrict__ v,
    float* __restrict__ sout)
{
  int s = blockIdx.x % cS; int h = (blockIdx.x / cS) % cH; int b = blockIdx.x / (cS * cH);
  int lane = threadIdx.x;
  __shared__ float qs[cDH];
  __shared__ float p[cWIN];
  qs[lane] = qr[(((size_t)b * cS + s) * cH + h) * cDH + lane];
  __syncthreads();
  float sc = -INFINITY;
  if (lane < cWIN) {
    int sp = s - lane;
    if (sp >= 0) {
      const float* kp = kr + (((size_t)b * cS + sp) * cH + h) * cDH;
      float a = 0.f;
      #pragma unroll 16
      for (int e = 0; e < cDH; e++) a += qs[e] * kp[e];
      sc = a * cSCALE;
    }
  }
  float mx = sc;
  #pragma unroll
  for (int o = 32; o; o >>= 1) mx = fmaxf(mx, __shfl_xor(mx, o));
  float ex = (sc == -INFINITY) ? 0.f : expf(sc - mx);
  float sum = ex;
  #pragma unroll
  for (int o = 32; o; o >>= 1) sum += __shfl_xor(sum, o);
  if (lane < cWIN) p[lane] = ex / sum;
  __syncthreads();
  float acc = 0.f;
  int wm = min(cWIN, s + 1);
  for (int w = 0; w < wm; w++)
    acc += p[w] * v[(((size_t)b * cS + s - w) * cH + h) * cDH + lane];
  sout[(((size_t)b * cS + s) * cH + h) * cDH + lane] = acc;
}

// ---------------- gated combine ----------------
__global__ __launch_bounds__(256) void k_combine(
    const float* __restrict__ gpre, const float* __restrict__ cout,
    const float* __restrict__ fout, const float* __restrict__ sout, float* __restrict__ o)
{
  int t = blockIdx.x * 256 + threadIdx.x; // < B*S*H*DH
  int hh = (t >> 6) & 15; int bs = t >> 10;
  float g0 = sigf(gpre[(size_t)bs * 48 + hh * 3 + 0]);
  float g1 = sigf(gpre[(size_t)bs * 48 + hh * 3 + 1]);
  float g2 = sigf(gpre[(size_t)bs * 48 + hh * 3 + 2]);
  o[t] = g0 * cout[t] + g1 * fout[t] + g2 * sout[t];
}

extern "C" void kernel_launch(void* const* d_in, const int* in_sizes, int n_in,
                              void* d_out, int out_size, void* d_ws, size_t ws_size,
                              hipStream_t stream) {
  float* out = (float*)d_out;

  // ---- guards with TRUE sizes (BS=4); failure encoded in fill magnitude ----
  static const int exp_sizes[17] = {
    2097152, 2097152, 2097152, 2,        // x, ve, x0, lambdas
    1048576, 1048576, 1048576,           // Wq, Wk, Wv
    4096, 4096,                          // pos_k, pos_v (H*BS*DH = 16*4*64)
    16384, 16384,                        // Wck, Wcv (BS*DH x DH = 256*64)
    1024, 1024,                          // mem_k, mem_v
    49152, 1048576, 4194304, 4194304     // Wg, Wo, Wfc, Wproj
  };
  if (n_in < 17) {
    k_fill<<<dim3(8192), dim3(256), 0, stream>>>(out, 500.0f + 10.0f * n_in);
    return;
  }
  for (int i = 0; i < 17; ++i) {
    if (in_sizes[i] != exp_sizes[i] && in_sizes[i] != 4 * exp_sizes[i]) {
      k_fill<<<dim3(8192), dim3(256), 0, stream>>>(out, 1000.0f + 50.0f * i);
      return;
    }
  }

  const float* x     = (const float*)d_in[0];
  const float* x0    = (const float*)d_in[2];
  const float* lam   = (const float*)d_in[3];
  const float* Wq    = (const float*)d_in[4];
  const float* Wk    = (const float*)d_in[5];
  const float* Wv    = (const float*)d_in[6];
  const float* pos_k = (const float*)d_in[7];
  const float* pos_v = (const float*)d_in[8];
  const float* Wck   = (const float*)d_in[9];
  const float* Wcv   = (const float*)d_in[10];
  const float* mem_k = (const float*)d_in[11];
  const float* mem_v = (const float*)d_in[12];
  const float* Wg    = (const float*)d_in[13];
  const float* Wo    = (const float*)d_in[14];
  const float* Wfc   = (const float*)d_in[15];
  const float* Wpr   = (const float*)d_in[16];

  // ws layout (f32 units): small area (gpre/selv/seli) in first 4MB; 9 big slots.
  // kc/vc live in slots 6/7 until cattn consumes them; fo/so reuse those slots after.
  // fc (4E) aliases slots 2..5 (q,k,v,co — dead by MLP). Total (1M + 9E)*4 = 76MB.
  float* ws = (float*)d_ws;
  const size_t E = (size_t)cM * cD; // 2097152
  float* gpre = ws;                                   // 98304
  float* selv = ws + 98304;                           // 131072
  int*   seli = (int*)(ws + 98304 + 131072);          // 131072
  const size_t A0 = 1048576;
  float* xr = ws + A0 + 0 * E;
  float* h  = ws + A0 + 1 * E; // reused as m after MLP rmsnorm
  float* q  = ws + A0 + 2 * E; // roped in place
  float* k  = ws + A0 + 3 * E;
  float* v  = ws + A0 + 4 * E;
  float* co = ws + A0 + 5 * E; // cout, then o
  float* fo = ws + A0 + 6 * E; // kc first, then fout
  float* so = ws + A0 + 7 * E; // vc first, then sout
  float* x1 = ws + A0 + 8 * E;
  float* fc = ws + A0 + 2 * E; // alias over q,k,v,co
  float* kc = fo;              // (B,257,H,DH) = 526336 floats <= E
  float* vc = so;

  dim3 b256(256), b64(64);
  dim3 gSq(cD / 64, cM / 64);

  k_lerp_rmsnorm<<<dim3(cM), b256, 0, stream>>>(x, x0, lam, xr, h);

  k_gemm<0><<<gSq, b256, 0, stream>>>(h, Wq, nullptr, q, cM, cD, cD);
  k_gemm<0><<<gSq, b256, 0, stream>>>(h, Wk, nullptr, k, cM, cD, cD);
  k_gemm<0><<<gSq, b256, 0, stream>>>(h, Wv, nullptr, v, cM, cD, cD);
  k_gemm<0><<<dim3(1, cM / 64), b256, 0, stream>>>(h, Wg, nullptr, gpre, cM, 48, cD);

  k_compress4<<<dim3(cB * cNBLK * cH), b64, 0, stream>>>(k, v, pos_k, pos_v, Wck, Wcv,
                                                         mem_k, mem_v, kc, vc);
  k_cattn4<<<dim3(cB * cH * cS), b64, 0, stream>>>(q, kc, vc, co, selv, seli);

  k_rope<<<dim3(cB * cS * cH * 32 / 256), b256, 0, stream>>>(q, k);

  k_fattn4<<<dim3(cB * cH * cS), b64, 0, stream>>>(q, k, v, selv, seli, fo);
  k_sattn<<<dim3(cB * cH * cS), b64, 0, stream>>>(q, k, v, so);

  k_combine<<<dim3((cM * cD) / 256), b256, 0, stream>>>(gpre, co, fo, so, co);

  k_gemm<0><<<gSq, b256, 0, stream>>>(co, Wo, xr, x1, cM, cD, cD);
  k_rmsnorm<<<dim3(cM), b256, 0, stream>>>(x1, h);
  k_gemm<1><<<dim3(cDFF / 64, cM / 64), b256, 0, stream>>>(h, Wfc, nullptr, fc, cM, cDFF, cD);
  k_gemm<0><<<gSq, b256, 0, stream>>>(fc, Wpr, x1, out, cM, cD, cDFF);
}

// Round 9
// 1392.463 us; speedup vs baseline: 1.2712x; 1.2712x over previous
//
#include <hip/hip_runtime.h>

// Problem constants — NOTE: BS=4 (H, DH, BS, NSEL, WIN = 16, 64, 4, 4, 32)
constexpr int cH = 16, cDH = 64, cBS = 4, cNSEL = 4, cWIN = 32;
constexpr int cB = 2, cS = 1024, cD = 1024;
constexpr int cNB = 256, cNBLK = 257, cDFF = 4096, cM = 2048; // cM = B*S
constexpr float cSCALE = 0.125f; // DH^-0.5

typedef unsigned short u16;
typedef unsigned int u32;

__device__ __forceinline__ float sigf(float x) { return 1.f / (1.f + expf(-x)); }
__device__ __forceinline__ float b2f(u16 u) {
  union { float f; u32 u; } c; c.u = ((u32)u) << 16; return c.f;
}
__device__ __forceinline__ u16 f2b(float f) {
  union { float f; u32 u; } c; c.f = f;
  u32 u = c.u;
  return (u16)((u + 0x7fffu + ((u >> 16) & 1u)) >> 16); // RNE
}

__global__ __launch_bounds__(256) void k_fill(float* __restrict__ p, float v)
{
  p[blockIdx.x * 256 + threadIdx.x] = v;
}

// ---------------- xr = l0*x + l1*x0 ; h = rmsnorm(xr) ----------------
__global__ __launch_bounds__(256) void k_lerp_rmsnorm(
    const float* __restrict__ x, const float* __restrict__ x0,
    const float* __restrict__ lambdas, float* __restrict__ xr, float* __restrict__ h)
{
  int row = blockIdx.x, tid = threadIdx.x;
  float l0 = lambdas[0], l1 = lambdas[1];
  size_t base = (size_t)row * cD + tid * 4;
  float4 xa = *(const float4*)(x + base);
  float4 xb = *(const float4*)(x0 + base);
  float v0 = l0 * xa.x + l1 * xb.x;
  float v1 = l0 * xa.y + l1 * xb.y;
  float v2 = l0 * xa.z + l1 * xb.z;
  float v3 = l0 * xa.w + l1 * xb.w;
  float ss = v0*v0 + v1*v1 + v2*v2 + v3*v3;
  #pragma unroll
  for (int o = 32; o; o >>= 1) ss += __shfl_xor(ss, o);
  __shared__ float red[4];
  if ((tid & 63) == 0) red[tid >> 6] = ss;
  __syncthreads();
  float tot = red[0] + red[1] + red[2] + red[3];
  float sc = rsqrtf(tot * (1.0f / cD) + 1e-6f);
  *(float4*)(xr + base) = make_float4(v0, v1, v2, v3);
  *(float4*)(h + base)  = make_float4(v0*sc, v1*sc, v2*sc, v3*sc);
}

// ---------------- out = rmsnorm(x) ----------------
__global__ __launch_bounds__(256) void k_rmsnorm(const float* __restrict__ x, float* __restrict__ out)
{
  int row = blockIdx.x, tid = threadIdx.x;
  size_t base = (size_t)row * cD + tid * 4;
  float4 v = *(const float4*)(x + base);
  float ss = v.x*v.x + v.y*v.y + v.z*v.z + v.w*v.w;
  #pragma unroll
  for (int o = 32; o; o >>= 1) ss += __shfl_xor(ss, o);
  __shared__ float red[4];
  if ((tid & 63) == 0) red[tid >> 6] = ss;
  __syncthreads();
  float tot = red[0] + red[1] + red[2] + red[3];
  float sc = rsqrtf(tot * (1.0f / cD) + 1e-6f);
  *(float4*)(out + base) = make_float4(v.x*sc, v.y*sc, v.z*sc, v.w*sc);
}

// ---------------- tiled f32 GEMM: C = epi(A@B) + R ; EPI: 0=none, 1=relu^2 ----------------
template<int EPI>
__global__ __launch_bounds__(256) void k_gemm(
    const float* __restrict__ A, const float* __restrict__ Bw,
    const float* __restrict__ R, float* __restrict__ C, int M, int N, int K)
{
  constexpr int BM = 64, BN = 64, BK = 16;
  __shared__ float As[BK][BM];
  __shared__ float Bs[BK][BN];
  int tid = threadIdx.x;
  int tx = tid & 15, ty = tid >> 4;
  int m0 = blockIdx.y * BM, n0 = blockIdx.x * BN;
  float acc[4][4] = {};
  for (int k0 = 0; k0 < K; k0 += BK) {
    {
      int r = tid >> 2, c4 = (tid & 3) << 2;
      float4 av = *(const float4*)(A + (size_t)(m0 + r) * K + k0 + c4);
      As[c4+0][r] = av.x; As[c4+1][r] = av.y; As[c4+2][r] = av.z; As[c4+3][r] = av.w;
    }
    {
      int kr = tid >> 4, c4 = (tid & 15) << 2;
      int n = n0 + c4;
      const float* bp = Bw + (size_t)(k0 + kr) * N;
      if (n + 3 < N) {
        float4 bv = *(const float4*)(bp + n);
        Bs[kr][c4+0] = bv.x; Bs[kr][c4+1] = bv.y; Bs[kr][c4+2] = bv.z; Bs[kr][c4+3] = bv.w;
      } else {
        #pragma unroll
        for (int j = 0; j < 4; j++) Bs[kr][c4+j] = (n + j < N) ? bp[n + j] : 0.f;
      }
    }
    __syncthreads();
    #pragma unroll
    for (int kk = 0; kk < BK; ++kk) {
      float4 a4 = *(const float4*)&As[kk][ty << 2];
      float4 b4 = *(const float4*)&Bs[kk][tx << 2];
      float av[4] = {a4.x, a4.y, a4.z, a4.w};
      float bv[4] = {b4.x, b4.y, b4.z, b4.w};
      #pragma unroll
      for (int i = 0; i < 4; i++)
        #pragma unroll
        for (int j = 0; j < 4; j++) acc[i][j] += av[i] * bv[j];
    }
    __syncthreads();
  }
  #pragma unroll
  for (int i = 0; i < 4; i++) {
    int m = m0 + (ty << 2) + i;
    #pragma unroll
    for (int j = 0; j < 4; j++) {
      int n = n0 + (tx << 2) + j;
      if (n < N) {
        float vv = acc[i][j];
        if (EPI == 1) vv = vv > 0.f ? vv * vv : 0.f;
        if (R) vv += R[(size_t)m * N + n];
        C[(size_t)m * N + n] = vv;
      }
    }
  }
}

// ---------------- block compression (BS=4): kc/vc (B,257,H,DH) ----------------
__global__ __launch_bounds__(64) void k_compress4(
    const float* __restrict__ kbuf, const float* __restrict__ vbuf,
    const float* __restrict__ pos_k, const float* __restrict__ pos_v,
    const float* __restrict__ Wck, const float* __restrict__ Wcv,
    const float* __restrict__ mem_k, const float* __restrict__ mem_v,
    float* __restrict__ kc, float* __restrict__ vc)
{
  int idx = blockIdx.x;          // b*NBLK*H + n*H + h
  int h = idx % cH; int n = (idx / cH) % cNBLK; int b = idx / (cH * cNBLK);
  int d = threadIdx.x;
  size_t co = (((size_t)b * cNBLK + n) * cH + h) * cDH + d;
  if (n == 0) {
    kc[co] = mem_k[h * cDH + d];
    vc[co] = mem_v[h * cDH + d];
    return;
  }
  __shared__ float kb[cBS * cDH], vb[cBS * cDH]; // 256 each
  int nb = n - 1;
  for (int t = d; t < cBS * cDH; t += 64) {
    int i = t >> 6, e = t & 63; // i<4
    size_t src = (((size_t)b * cS + nb * cBS + i) * cH + h) * cDH + e;
    kb[t] = kbuf[src] + pos_k[(h * cBS + i) * cDH + e];
    vb[t] = vbuf[src] + pos_v[(h * cBS + i) * cDH + e];
  }
  __syncthreads();
  float ak = 0.f, av = 0.f;
  for (int j = 0; j < cBS * cDH; ++j) { // Wck: (256,64)
    ak += kb[j] * Wck[(size_t)j * cDH + d];
    av += vb[j] * Wcv[(size_t)j * cDH + d];
  }
  kc[co] = ak; vc[co] = av;
}

// ---------------- tiled compressed attention: wg = (b, h, 64-row s-tile) ----------------
// 4 waves; wave c owns cols [c*65, min(257,c*65+65)); lane = row within tile.
// Raw scores -> bf16 LDS; top-4 kept in f32 regs (selection exact); e overwrites LDS;
// cout accumulated per (row, d-quarter) with normalization folded into final scale.
__global__ __launch_bounds__(256) void k_cattn_tile(
    const float* __restrict__ q, const float* __restrict__ kc, const float* __restrict__ vc,
    float* __restrict__ cout, float* __restrict__ sel_val, int* __restrict__ sel_idx)
{
  constexpr int SSTR = 258; // even stride: bank = (r + n/2)&31 -> 2 lanes/bank (free)
  __shared__ u16  ssb[64 * SSTR];  // scores, then e (bf16)
  __shared__ float lmax[4][64];
  __shared__ float lsum[4][64];
  __shared__ float t4v[4][64][4];
  __shared__ int   t4i[4][64][4];
  __shared__ float mxs[64];
  __shared__ float invs[64];

  int tile = blockIdx.x & 15;
  int h = (blockIdx.x >> 4) & 15;
  int b = blockIdx.x >> 8;
  int s0 = tile * 64;
  int t = threadIdx.x;
  int lane = t & 63, wave = t >> 6;

  const float* kcb = kc + ((size_t)b * cNBLK * cH + h) * cDH;
  const float* vcb = vc + ((size_t)b * cNBLK * cH + h) * cDH;
  const int nstride = cH * cDH; // 1024 floats between n rows

  // phase 1: scores; q row in registers, kc rows broadcast
  {
    int r = lane;
    int s_row = s0 + r;
    const float* qrow = q + (((size_t)b * cS + s_row) * cH + h) * cDH;
    float4 qr[16];
    #pragma unroll
    for (int f = 0; f < 16; f++) qr[f] = ((const float4*)qrow)[f];
    float v0=-INFINITY,v1=-INFINITY,v2=-INFINITY,v3=-INFINITY;
    int i0=0,i1=0,i2=0,i3=0;
    float lm = -INFINITY;
    int nb0 = wave * 65;
    int nb1 = min(cNBLK, nb0 + 65);
    for (int n = nb0; n < nb1; n++) {
      const float4* kp = (const float4*)(kcb + (size_t)n * nstride);
      float a = 0.f;
      #pragma unroll
      for (int f = 0; f < 16; f++) {
        float4 k4 = kp[f];
        a += qr[f].x*k4.x + qr[f].y*k4.y + qr[f].z*k4.z + qr[f].w*k4.w;
      }
      a *= cSCALE;
      bool vis = (n == 0) || ((n - 1) * cBS + (cBS - 1) <= s_row);
      float sv = vis ? a : -INFINITY;
      ssb[r * SSTR + n] = f2b(sv);
      lm = fmaxf(lm, sv);
      if (n >= 1 && sv > v3) {
        int bi = n - 1;
        if (sv > v0)      { v3=v2;i3=i2; v2=v1;i2=i1; v1=v0;i1=i0; v0=sv;i0=bi; }
        else if (sv > v1) { v3=v2;i3=i2; v2=v1;i2=i1; v1=sv;i1=bi; }
        else if (sv > v2) { v3=v2;i3=i2; v2=sv;i2=bi; }
        else              { v3=sv;i3=bi; }
      }
    }
    lmax[wave][lane] = lm;
    t4v[wave][lane][0]=v0; t4v[wave][lane][1]=v1; t4v[wave][lane][2]=v2; t4v[wave][lane][3]=v3;
    t4i[wave][lane][0]=i0; t4i[wave][lane][1]=i1; t4i[wave][lane][2]=i2; t4i[wave][lane][3]=i3;
  }
  __syncthreads();

  // phase 2a: wave 0 — row max + merge 16 top-4 candidates (scan order = ascending n)
  if (wave == 0) {
    int r = lane;
    float mx = fmaxf(fmaxf(lmax[0][r], lmax[1][r]), fmaxf(lmax[2][r], lmax[3][r]));
    mxs[r] = mx;
    float v0=-INFINITY,v1=-INFINITY,v2=-INFINITY,v3=-INFINITY;
    int i0=0,i1=0,i2=0,i3=0;
    #pragma unroll
    for (int c = 0; c < 4; c++)
      #pragma unroll
      for (int u = 0; u < 4; u++) {
        float sv = t4v[c][r][u]; int bi = t4i[c][r][u];
        if (sv > v3) {
          if (sv > v0)      { v3=v2;i3=i2; v2=v1;i2=i1; v1=v0;i1=i0; v0=sv;i0=bi; }
          else if (sv > v1) { v3=v2;i3=i2; v2=v1;i2=i1; v1=sv;i1=bi; }
          else if (sv > v2) { v3=v2;i3=i2; v2=sv;i2=bi; }
          else              { v3=sv;i3=bi; }
        }
      }
    t4v[0][r][0]=v0; t4v[0][r][1]=v1; t4v[0][r][2]=v2; t4v[0][r][3]=v3;
    t4i[0][r][0]=i0; t4i[0][r][1]=i1; t4i[0][r][2]=i2; t4i[0][r][3]=i3;
  }
  __syncthreads();

  // phase 2b: e = exp(s - mx) overwrites ssb; partial row sums
  {
    int r = lane;
    float mx = mxs[r];
    float s = 0.f;
    int nb0 = wave * 65;
    int nb1 = min(cNBLK, nb0 + 65);
    for (int n = nb0; n < nb1; n++) {
      float sv = b2f(ssb[r * SSTR + n]);
      float e = expf(sv - mx); // exp(-inf - mx) = 0
      ssb[r * SSTR + n] = f2b(e);
      s += e;
    }
    lsum[wave][r] = s;
  }
  __syncthreads();

  // phase 2c: wave 0 — inv sum; write sel_val/sel_idx
  if (wave == 0) {
    int r = lane;
    float sum = lsum[0][r] + lsum[1][r] + lsum[2][r] + lsum[3][r];
    float inv = 1.f / sum;
    invs[r] = inv;
    float mx = mxs[r];
    size_t so = (((size_t)b * cH + h) * cS + (s0 + r)) * cNSEL;
    #pragma unroll
    for (int u = 0; u < 4; u++) {
      sel_val[so + u] = expf(t4v[0][r][u] - mx) * inv; // 0 for -inf sentinels
      sel_idx[so + u] = t4i[0][r][u];
    }
  }
  __syncthreads();

  // phase 4: cout[r][d]; thread t: r = t>>2, dq = t&3 -> d = dq*16..dq*16+15
  {
    int r = t >> 2, dq = t & 3;
    float4 a0 = {0,0,0,0}, a1 = {0,0,0,0}, a2 = {0,0,0,0}, a3 = {0,0,0,0};
    const u16* erow = ssb + r * SSTR;
    const float* vbase = vcb + dq * 16;
    for (int n = 0; n < cNBLK; n++) {
      float e = b2f(erow[n]);
      const float4* vp = (const float4*)(vbase + (size_t)n * nstride);
      float4 w0 = vp[0], w1 = vp[1], w2 = vp[2], w3 = vp[3];
      a0.x += e*w0.x; a0.y += e*w0.y; a0.z += e*w0.z; a0.w += e*w0.w;
      a1.x += e*w1.x; a1.y += e*w1.y; a1.z += e*w1.z; a1.w += e*w1.w;
      a2.x += e*w2.x; a2.y += e*w2.y; a2.z += e*w2.z; a2.w += e*w2.w;
      a3.x += e*w3.x; a3.y += e*w3.y; a3.z += e*w3.z; a3.w += e*w3.w;
    }
    float inv = invs[r];
    float* crow = cout + (((size_t)b * cS + s0 + r) * cH + h) * cDH + dq * 16;
    ((float4*)crow)[0] = make_float4(a0.x*inv, a0.y*inv, a0.z*inv, a0.w*inv);
    ((float4*)crow)[1] = make_float4(a1.x*inv, a1.y*inv, a1.z*inv, a1.w*inv);
    ((float4*)crow)[2] = make_float4(a2.x*inv, a2.y*inv, a2.z*inv, a2.w*inv);
    ((float4*)crow)[3] = make_float4(a3.x*inv, a3.y*inv, a3.z*inv, a3.w*inv);
  }
}

// ---------------- in-place RoPE on q and k ----------------
__global__ __launch_bounds__(256) void k_rope(float* __restrict__ q, float* __restrict__ k)
{
  int t = blockIdx.x * 256 + threadIdx.x; // < B*S*H*32
  int j = t & 31; int h = (t >> 5) & (cH - 1); int bs = t >> 9;
  int s = bs & (cS - 1);
  float inv = expf(-(float)j * 0.28782313662425575f); // ln(10000)/32
  float ang = (float)s * inv;
  float sn, c; sincosf(ang, &sn, &c);
  size_t base = ((size_t)bs * cH + h) * cDH;
  float q1 = q[base + j], q2 = q[base + j + 32];
  q[base + j]      = q1 * c - q2 * sn;
  q[base + j + 32] = q1 * sn + q2 * c;
  float k1 = k[base + j], k2 = k[base + j + 32];
  k[base + j]      = k1 * c - k2 * sn;
  k[base + j + 32] = k1 * sn + k2 * c;
}

// ---------------- fine attention: 5 blocks x 4 keys = 20 ----------------
__global__ __launch_bounds__(64) void k_fattn4(
    const float* __restrict__ qr, const float* __restrict__ kr, const float* __restrict__ v,
    const float* __restrict__ sel_val, const int* __restrict__ sel_idx,
    float* __restrict__ fout)
{
  int s = blockIdx.x % cS; int h = (blockIdx.x / cS) % cH; int b = blockIdx.x / (cS * cH);
  int lane = threadIdx.x;
  const int NK = 5 * cBS; // 20
  __shared__ float qs[cDH];
  __shared__ float p[NK];
  __shared__ int blk[5];
  __shared__ int bok[5];
  qs[lane] = qr[(((size_t)b * cS + s) * cH + h) * cDH + lane];
  if (lane < 5) {
    size_t so = (((size_t)b * cH + h) * cS + s) * cNSEL;
    if (lane < 4) { blk[lane] = sel_idx[so + lane]; bok[lane] = sel_val[so + lane] > 0.f; }
    else          { blk[4] = s / cBS; bok[4] = 1; }
  }
  __syncthreads();
  float sc = -INFINITY;
  if (lane < NK) {
    int t = lane >> 2, i = lane & 3;
    int kpos = blk[t] * cBS + i;
    if (bok[t] && kpos <= s) {
      const float* kp = kr + (((size_t)b * cS + kpos) * cH + h) * cDH;
      float a = 0.f;
      #pragma unroll 16
      for (int e = 0; e < cDH; e++) a += qs[e] * kp[e];
      sc = a * cSCALE;
    }
  }
  float mx = sc;
  #pragma unroll
  for (int o = 32; o; o >>= 1) mx = fmaxf(mx, __shfl_xor(mx, o));
  float ex = (sc == -INFINITY) ? 0.f : expf(sc - mx);
  float sum = ex;
  #pragma unroll
  for (int o = 32; o; o >>= 1) sum += __shfl_xor(sum, o);
  if (lane < NK) p[lane] = ex / sum;
  __syncthreads();
  float acc = 0.f;
  for (int t = 0; t < 5; t++) {
    if (!bok[t]) continue; // wave-uniform
    int kbase = blk[t] * cBS;
    #pragma unroll
    for (int i = 0; i < cBS; i++) {
      float pm = p[t * cBS + i];
      if (pm != 0.f)
        acc += pm * v[(((size_t)b * cS + kbase + i) * cH + h) * cDH + lane];
    }
  }
  fout[(((size_t)b * cS + s) * cH + h) * cDH + lane] = acc;
}

// ---------------- sliding-window attention (WIN=32) ----------------
__global__ __launch_bounds__(64) void k_sattn(
    const float* __restrict__ qr, const float* __restrict__ kr, const float* __restrict__ v,
    float* __restrict__ sout)
{
  int s = blockIdx.x % cS; int h = (blockIdx.x / cS) % cH; int b = blockIdx.x / (cS * cH);
  int lane = threadIdx.x;
  __shared__ float qs[cDH];
  __shared__ float p[cWIN];
  qs[lane] = qr[(((size_t)b * cS + s) * cH + h) * cDH + lane];
  __syncthreads();
  float sc = -INFINITY;
  if (lane < cWIN) {
    int sp = s - lane;
    if (sp >= 0) {
      const float* kp = kr + (((size_t)b * cS + sp) * cH + h) * cDH;
      float a = 0.f;
      #pragma unroll 16
      for (int e = 0; e < cDH; e++) a += qs[e] * kp[e];
      sc = a * cSCALE;
    }
  }
  float mx = sc;
  #pragma unroll
  for (int o = 32; o; o >>= 1) mx = fmaxf(mx, __shfl_xor(mx, o));
  float ex = (sc == -INFINITY) ? 0.f : expf(sc - mx);
  float sum = ex;
  #pragma unroll
  for (int o = 32; o; o >>= 1) sum += __shfl_xor(sum, o);
  if (lane < cWIN) p[lane] = ex / sum;
  __syncthreads();
  float acc = 0.f;
  int wm = min(cWIN, s + 1);
  for (int w = 0; w < wm; w++)
    acc += p[w] * v[(((size_t)b * cS + s - w) * cH + h) * cDH + lane];
  sout[(((size_t)b * cS + s) * cH + h) * cDH + lane] = acc;
}

// ---------------- gated combine ----------------
__global__ __launch_bounds__(256) void k_combine(
    const float* __restrict__ gpre, const float* __restrict__ cout,
    const float* __restrict__ fout, const float* __restrict__ sout, float* __restrict__ o)
{
  int t = blockIdx.x * 256 + threadIdx.x; // < B*S*H*DH
  int hh = (t >> 6) & 15; int bs = t >> 10;
  float g0 = sigf(gpre[(size_t)bs * 48 + hh * 3 + 0]);
  float g1 = sigf(gpre[(size_t)bs * 48 + hh * 3 + 1]);
  float g2 = sigf(gpre[(size_t)bs * 48 + hh * 3 + 2]);
  o[t] = g0 * cout[t] + g1 * fout[t] + g2 * sout[t];
}

extern "C" void kernel_launch(void* const* d_in, const int* in_sizes, int n_in,
                              void* d_out, int out_size, void* d_ws, size_t ws_size,
                              hipStream_t stream) {
  float* out = (float*)d_out;

  // ---- guards (BS=4 sizes); failure encoded in fill magnitude ----
  static const int exp_sizes[17] = {
    2097152, 2097152, 2097152, 2,
    1048576, 1048576, 1048576,
    4096, 4096,
    16384, 16384,
    1024, 1024,
    49152, 1048576, 4194304, 4194304
  };
  if (n_in < 17) {
    k_fill<<<dim3(8192), dim3(256), 0, stream>>>(out, 500.0f + 10.0f * n_in);
    return;
  }
  for (int i = 0; i < 17; ++i) {
    if (in_sizes[i] != exp_sizes[i] && in_sizes[i] != 4 * exp_sizes[i]) {
      k_fill<<<dim3(8192), dim3(256), 0, stream>>>(out, 1000.0f + 50.0f * i);
      return;
    }
  }

  const float* x     = (const float*)d_in[0];
  const float* x0    = (const float*)d_in[2];
  const float* lam   = (const float*)d_in[3];
  const float* Wq    = (const float*)d_in[4];
  const float* Wk    = (const float*)d_in[5];
  const float* Wv    = (const float*)d_in[6];
  const float* pos_k = (const float*)d_in[7];
  const float* pos_v = (const float*)d_in[8];
  const float* Wck   = (const float*)d_in[9];
  const float* Wcv   = (const float*)d_in[10];
  const float* mem_k = (const float*)d_in[11];
  const float* mem_v = (const float*)d_in[12];
  const float* Wg    = (const float*)d_in[13];
  const float* Wo    = (const float*)d_in[14];
  const float* Wfc   = (const float*)d_in[15];
  const float* Wpr   = (const float*)d_in[16];

  // ws layout identical to R8 (passed): (1M + 9E)*4 = 76MB.
  float* ws = (float*)d_ws;
  const size_t E = (size_t)cM * cD; // 2097152
  float* gpre = ws;                                   // 98304
  float* selv = ws + 98304;                           // 131072
  int*   seli = (int*)(ws + 98304 + 131072);          // 131072
  const size_t A0 = 1048576;
  float* xr = ws + A0 + 0 * E;
  float* h  = ws + A0 + 1 * E; // reused as m after MLP rmsnorm
  float* q  = ws + A0 + 2 * E; // roped in place
  float* k  = ws + A0 + 3 * E;
  float* v  = ws + A0 + 4 * E;
  float* co = ws + A0 + 5 * E; // cout, then o
  float* fo = ws + A0 + 6 * E; // kc first, then fout
  float* so = ws + A0 + 7 * E; // vc first, then sout
  float* x1 = ws + A0 + 8 * E;
  float* fc = ws + A0 + 2 * E; // alias over q,k,v,co
  float* kc = fo;              // (B,257,H,DH) = 526336 floats <= E
  float* vc = so;

  dim3 b256(256), b64(64);
  dim3 gSq(cD / 64, cM / 64);

  k_lerp_rmsnorm<<<dim3(cM), b256, 0, stream>>>(x, x0, lam, xr, h);

  k_gemm<0><<<gSq, b256, 0, stream>>>(h, Wq, nullptr, q, cM, cD, cD);
  k_gemm<0><<<gSq, b256, 0, stream>>>(h, Wk, nullptr, k, cM, cD, cD);
  k_gemm<0><<<gSq, b256, 0, stream>>>(h, Wv, nullptr, v, cM, cD, cD);
  k_gemm<0><<<dim3(1, cM / 64), b256, 0, stream>>>(h, Wg, nullptr, gpre, cM, 48, cD);

  k_compress4<<<dim3(cB * cNBLK * cH), b64, 0, stream>>>(k, v, pos_k, pos_v, Wck, Wcv,
                                                         mem_k, mem_v, kc, vc);
  // tiled cattn: wg per (b, h, 64-row tile) => grid 2*16*16 = 512
  k_cattn_tile<<<dim3(cB * cH * 16), b256, 0, stream>>>(q, kc, vc, co, selv, seli);

  k_rope<<<dim3(cB * cS * cH * 32 / 256), b256, 0, stream>>>(q, k);

  k_fattn4<<<dim3(cB * cH * cS), b64, 0, stream>>>(q, k, v, selv, seli, fo);
  k_sattn<<<dim3(cB * cH * cS), b64, 0, stream>>>(q, k, v, so);

  k_combine<<<dim3((cM * cD) / 256), b256, 0, stream>>>(gpre, co, fo, so, co);

  k_gemm<0><<<gSq, b256, 0, stream>>>(co, Wo, xr, x1, cM, cD, cD);
  k_rmsnorm<<<dim3(cM), b256, 0, stream>>>(x1, h);
  k_gemm<1><<<dim3(cDFF / 64, cM / 64), b256, 0, stream>>>(h, Wfc, nullptr, fc, cM, cDFF, cD);
  k_gemm<0><<<gSq, b256, 0, stream>>>(fc, Wpr, x1, out, cM, cD, cDFF);
}